// Round 4
// baseline (213.708 us; speedup 1.0000x reference)
//
#include <hip/hip_runtime.h>

#define HDIM 1024
#define WDIM 1024
#define NPIX (HDIM*WDIM)
#define KDIM 5
#define KK 25
#define TX 32
#define TY 4
#define NTHR (TX*TY)           // 128
#define PXT 4                  // pixels per thread
#define TILEW (TX*PXT)         // 128
#define TROWS (TY + 4)         // 8
#define NF4 34                 // staged f4 per row: cols [bx-4, bx+132)
#define TCOLS 140              // 136 used + 4 pad floats

typedef float f4 __attribute__((ext_vector_type(4)));

__global__ __launch_bounds__(NTHR, 8) void fused_step(
    const float* __restrict__ x,     // 6*N  [spike, V, R, A, T, E]
    const float* __restrict__ EI,    // N
    const float* __restrict__ nnk,   // 25*N
    const float* __restrict__ trm,   // N
    const float* __restrict__ ksI,   // N
    const float* __restrict__ ksE,   // N
    float* __restrict__ out)         // 32*N  [z(7N), new_k(25N)]
{
#pragma clang fp contract(off)
    __shared__ __align__(16) float s0t[TROWS][TCOLS];
    __shared__ __align__(16) float at [TROWS][TCOLS];

    const int bx  = blockIdx.x * TILEW;
    const int by  = blockIdx.y * TY;
    const int tid = threadIdx.y * TX + threadIdx.x;
    const int lx  = threadIdx.x;
    const int ly  = threadIdx.y;
    const int n   = (by + ly) * WDIM + bx + lx * PXT;

    // vectorized halo staging: aligned f4, circular wrap (bases stay 4-aligned)
    for (int idx = tid; idx < TROWS * NF4; idx += NTHR) {
        int r  = idx / NF4;
        int t  = idx - r * NF4;
        int gy = (by + r - 2) & (HDIM - 1);
        int gx = (bx - 4 + t * 4) & (WDIM - 1);
        int g  = gy * WDIM + gx;
        f4 x0 = *reinterpret_cast<const f4*>(&x[g]);
        f4 ev = *reinterpret_cast<const f4*>(&EI[g]);
        f4 a3 = *reinterpret_cast<const f4*>(&x[3 * NPIX + g]);
        f4 s0;
        #pragma unroll
        for (int q = 0; q < 4; ++q) s0[q] = x0[q] * ev[q];
        *reinterpret_cast<f4*>(&s0t[r][t * 4]) = s0;
        *reinterpret_cast<f4*>(&at [r][t * 4]) = a3;
    }
    __syncthreads();

    // LDS col c maps to gx = bx-4+c; tap (j) for pixel q at c = lx*4 + q + j + 2

    // P1: conv accumulate, streaming nn_k (nothing kept)
    f4 I = {0.0f, 0.0f, 0.0f, 0.0f};
    #pragma unroll
    for (int i = 0; i < KDIM; ++i) {
        const float* row = &s0t[ly + i][lx * PXT];
        f4 e0 = *reinterpret_cast<const f4*>(row);
        f4 e1 = *reinterpret_cast<const f4*>(row + 4);
        f4 e2 = *reinterpret_cast<const f4*>(row + 8);
        float e[12] = {e0[0],e0[1],e0[2],e0[3], e1[0],e1[1],e1[2],e1[3],
                       e2[0],e2[1],e2[2],e2[3]};
        #pragma unroll
        for (int j = 0; j < KDIM; ++j) {
            f4 nkv = *reinterpret_cast<const f4*>(&nnk[(i * KDIM + j) * NPIX + n]);
            #pragma unroll
            for (int q = 0; q < PXT; ++q) {
                float p = e[2 + q + j] * nkv[q];
                I[q] = I[q] + p;
            }
        }
    }

    // pointwise neuron update
    f4 V  = *reinterpret_cast<const f4*>(&x[1 * NPIX + n]);
    f4 R  = *reinterpret_cast<const f4*>(&x[2 * NPIX + n]);
    f4 A  = *reinterpret_cast<const f4*>(&x[3 * NPIX + n]);
    f4 T  = *reinterpret_cast<const f4*>(&x[4 * NPIX + n]);
    f4 E  = *reinterpret_cast<const f4*>(&x[5 * NPIX + n]);
    f4 ei = *reinterpret_cast<const f4*>(&EI[n]);
    f4 tr = *reinterpret_cast<const f4*>(&trm[n]);
    f4 kI = *reinterpret_cast<const f4*>(&ksI[n]);
    f4 kE = *reinterpret_cast<const f4*>(&ksE[n]);

    f4 S, Vo, Rn, An, Tn, En, fac;
    #pragma unroll
    for (int q = 0; q < PXT; ++q) {
        float v = (V[q] - 0.2f * V[q]) + 4.0f * I[q];
        float s = (v > T[q] && R[q] > 5.0f && E[q] > 0.1f) ? 1.0f : 0.0f;
        En[q] = (E[q] + 0.0058f * (1.0f - E[q])) - s * 0.1f;
        Rn[q] = (R[q] + 1.0f) * (1.0f - s);
        float an = (A[q] - A[q] / 100.0f) + s;
        An[q] = an;
        Tn[q] = (T[q] - T[q] / 1000.0f) + 0.05f * (an - tr[q]);
        Vo[q] = v * (1.0f - s);
        S[q]  = s;
        float ei_neg = (ei[q] < 0.0f) ? 1.0f : 0.0f;
        fac[q] = an - tr[q] * ei_neg;
    }

    // store z NOW to free the state registers
    __builtin_nontemporal_store(S,  reinterpret_cast<f4*>(&out[0 * NPIX + n]));
    __builtin_nontemporal_store(Vo, reinterpret_cast<f4*>(&out[1 * NPIX + n]));
    __builtin_nontemporal_store(Rn, reinterpret_cast<f4*>(&out[2 * NPIX + n]));
    __builtin_nontemporal_store(An, reinterpret_cast<f4*>(&out[3 * NPIX + n]));
    __builtin_nontemporal_store(Tn, reinterpret_cast<f4*>(&out[4 * NPIX + n]));
    __builtin_nontemporal_store(En, reinterpret_cast<f4*>(&out[5 * NPIX + n]));
    __builtin_nontemporal_store(ei, reinterpret_cast<f4*>(&out[6 * NPIX + n]));

    // P2: colsum pass, streaming nn_k again (L2-resident slice)
    f4 colsum = {0.0f, 0.0f, 0.0f, 0.0f};
    #pragma unroll
    for (int i = 0; i < KDIM; ++i) {
        const float* row = &at[ly + i][lx * PXT];
        f4 e0 = *reinterpret_cast<const f4*>(row);
        f4 e1 = *reinterpret_cast<const f4*>(row + 4);
        f4 e2 = *reinterpret_cast<const f4*>(row + 8);
        float e[12] = {e0[0],e0[1],e0[2],e0[3], e1[0],e1[1],e1[2],e1[3],
                       e2[0],e2[1],e2[2],e2[3]};
        #pragma unroll
        for (int j = 0; j < KDIM; ++j) {
            const int kk = i * KDIM + j;
            f4 nkv = *reinterpret_cast<const f4*>(&nnk[kk * NPIX + n]);
            #pragma unroll
            for (int q = 0; q < PXT; ++q) {
                float d = (nkv[q] > 1e-6f) ? e[2 + q + j] * fac[q] : 0.0f;
                float v = nkv[q] + 0.01f * d;
                v = fmaxf(v, 0.0f);
                if (kk == KK / 2) v = 0.0f;
                colsum[q] += v;
            }
        }
    }

    f4 scale;
    #pragma unroll
    for (int q = 0; q < PXT; ++q) {
        float ks = (ei[q] < 0.0f) ? kI[q] : kE[q];
        scale[q] = ks / (colsum[q] + 1e-6f);
    }

    // P3: recompute (bit-identical) and store scaled weights
    #pragma unroll
    for (int i = 0; i < KDIM; ++i) {
        const float* row = &at[ly + i][lx * PXT];
        f4 e0 = *reinterpret_cast<const f4*>(row);
        f4 e1 = *reinterpret_cast<const f4*>(row + 4);
        f4 e2 = *reinterpret_cast<const f4*>(row + 8);
        float e[12] = {e0[0],e0[1],e0[2],e0[3], e1[0],e1[1],e1[2],e1[3],
                       e2[0],e2[1],e2[2],e2[3]};
        #pragma unroll
        for (int j = 0; j < KDIM; ++j) {
            const int kk = i * KDIM + j;
            f4 nkv = *reinterpret_cast<const f4*>(&nnk[kk * NPIX + n]);
            f4 vout;
            #pragma unroll
            for (int q = 0; q < PXT; ++q) {
                float d = (nkv[q] > 1e-6f) ? e[2 + q + j] * fac[q] : 0.0f;
                float v = nkv[q] + 0.01f * d;
                v = fmaxf(v, 0.0f);
                if (kk == KK / 2) v = 0.0f;
                vout[q] = v * scale[q];
            }
            __builtin_nontemporal_store(vout,
                reinterpret_cast<f4*>(&out[(7 + kk) * NPIX + n]));
        }
    }
}

extern "C" void kernel_launch(void* const* d_in, const int* in_sizes, int n_in,
                              void* d_out, int out_size, void* d_ws, size_t ws_size,
                              hipStream_t stream) {
    const float* x    = (const float*)d_in[0];
    const float* EI   = (const float*)d_in[2];
    const float* nnk  = (const float*)d_in[3];
    const float* trm  = (const float*)d_in[4];
    const float* ksI  = (const float*)d_in[6];
    const float* ksE  = (const float*)d_in[7];
    float* out = (float*)d_out;

    dim3 block(TX, TY);
    dim3 grid(WDIM / TILEW, HDIM / TY);   // 8 x 256 = 2048 blocks
    fused_step<<<grid, block, 0, stream>>>(x, EI, nnk, trm, ksI, ksE, out);
}

// Round 5
// 195.648 us; speedup vs baseline: 1.0923x; 1.0923x over previous
//
#include <hip/hip_runtime.h>

#define HDIM 1024
#define WDIM 1024
#define NPIX (HDIM*WDIM)
#define KDIM 5
#define KK 25
#define TX 32
#define TY 8
#define NTHR (TX*TY)           // 256
#define PXT 2                  // pixels per thread
#define TILEW (TX*PXT)         // 64
#define TROWS (TY + 4)         // 12
#define NF4 18                 // staged f4 per row: cols [bx-4, bx+68)
#define TCOLS 76               // 72 used + 4 pad floats (16B-multiple stride)

typedef float f4 __attribute__((ext_vector_type(4)));
typedef float f2 __attribute__((ext_vector_type(2)));

__global__ __launch_bounds__(NTHR, 8) void fused_step(
    const float* __restrict__ x,     // 6*N  [spike, V, R, A, T, E]
    const float* __restrict__ EI,    // N
    const float* __restrict__ nnk,   // 25*N
    const float* __restrict__ trm,   // N
    const float* __restrict__ ksI,   // N
    const float* __restrict__ ksE,   // N
    float* __restrict__ out)         // 32*N  [z(7N), new_k(25N)]
{
#pragma clang fp contract(off)
    __shared__ __align__(16) float s0t[TROWS][TCOLS];
    __shared__ __align__(16) float at [TROWS][TCOLS];

    const int bx  = blockIdx.x * TILEW;
    const int by  = blockIdx.y * TY;
    const int tid = threadIdx.y * TX + threadIdx.x;
    const int lx  = threadIdx.x;
    const int ly  = threadIdx.y;
    const int n   = (by + ly) * WDIM + bx + lx * PXT;

    // Issue pointwise-state loads first: they don't depend on LDS, so they
    // overlap the halo staging + barrier below.
    f2 V  = *reinterpret_cast<const f2*>(&x[1 * NPIX + n]);
    f2 R  = *reinterpret_cast<const f2*>(&x[2 * NPIX + n]);
    f2 A  = *reinterpret_cast<const f2*>(&x[3 * NPIX + n]);
    f2 T  = *reinterpret_cast<const f2*>(&x[4 * NPIX + n]);
    f2 E  = *reinterpret_cast<const f2*>(&x[5 * NPIX + n]);
    f2 ei = *reinterpret_cast<const f2*>(&EI[n]);
    f2 tr = *reinterpret_cast<const f2*>(&trm[n]);
    f2 kI = *reinterpret_cast<const f2*>(&ksI[n]);
    f2 kE = *reinterpret_cast<const f2*>(&ksE[n]);

    // vectorized halo staging: aligned f4, circular wrap (bases 4-aligned)
    for (int idx = tid; idx < TROWS * NF4; idx += NTHR) {
        int r  = idx / NF4;
        int t  = idx - r * NF4;
        int gy = (by + r - 2) & (HDIM - 1);
        int gx = (bx - 4 + t * 4) & (WDIM - 1);
        int g  = gy * WDIM + gx;
        f4 x0 = *reinterpret_cast<const f4*>(&x[g]);
        f4 ev = *reinterpret_cast<const f4*>(&EI[g]);
        f4 a3 = *reinterpret_cast<const f4*>(&x[3 * NPIX + g]);
        f4 s0;
        #pragma unroll
        for (int q = 0; q < 4; ++q) s0[q] = x0[q] * ev[q];
        *reinterpret_cast<f4*>(&s0t[r][t * 4]) = s0;
        *reinterpret_cast<f4*>(&at [r][t * 4]) = a3;
    }
    __syncthreads();

    // LDS col c maps to gx = bx-4+c; tap for pixel q, offset j: c = lx*2+2+q+j

    // P1: conv accumulate, streaming nn_k
    f2 I = {0.0f, 0.0f};
    #pragma unroll
    for (int i = 0; i < KDIM; ++i) {
        const float* row = &s0t[ly + i][lx * PXT + 2];
        float ta[6];
        #pragma unroll
        for (int m = 0; m < 6; ++m) ta[m] = row[m];
        #pragma unroll
        for (int j = 0; j < KDIM; ++j) {
            f2 nkv = *reinterpret_cast<const f2*>(&nnk[(i * KDIM + j) * NPIX + n]);
            #pragma unroll
            for (int q = 0; q < PXT; ++q) {
                float p = ta[q + j] * nkv[q];
                I[q] = I[q] + p;
            }
        }
    }

    f2 S, Vo, Rn, An, Tn, En, fac;
    #pragma unroll
    for (int q = 0; q < PXT; ++q) {
        float v = (V[q] - 0.2f * V[q]) + 4.0f * I[q];
        float s = (v > T[q] && R[q] > 5.0f && E[q] > 0.1f) ? 1.0f : 0.0f;
        En[q] = (E[q] + 0.0058f * (1.0f - E[q])) - s * 0.1f;
        Rn[q] = (R[q] + 1.0f) * (1.0f - s);
        float an = (A[q] - A[q] / 100.0f) + s;
        An[q] = an;
        Tn[q] = (T[q] - T[q] / 1000.0f) + 0.05f * (an - tr[q]);
        Vo[q] = v * (1.0f - s);
        S[q]  = s;
        float ei_neg = (ei[q] < 0.0f) ? 1.0f : 0.0f;
        fac[q] = an - tr[q] * ei_neg;
    }

    // store z now to free state registers
    __builtin_nontemporal_store(S,  reinterpret_cast<f2*>(&out[0 * NPIX + n]));
    __builtin_nontemporal_store(Vo, reinterpret_cast<f2*>(&out[1 * NPIX + n]));
    __builtin_nontemporal_store(Rn, reinterpret_cast<f2*>(&out[2 * NPIX + n]));
    __builtin_nontemporal_store(An, reinterpret_cast<f2*>(&out[3 * NPIX + n]));
    __builtin_nontemporal_store(Tn, reinterpret_cast<f2*>(&out[4 * NPIX + n]));
    __builtin_nontemporal_store(En, reinterpret_cast<f2*>(&out[5 * NPIX + n]));
    __builtin_nontemporal_store(ei, reinterpret_cast<f2*>(&out[6 * NPIX + n]));

    // P2: colsum pass, streaming nn_k again (block slice is L2-hot, 51KB)
    f2 colsum = {0.0f, 0.0f};
    #pragma unroll
    for (int i = 0; i < KDIM; ++i) {
        const float* row = &at[ly + i][lx * PXT + 2];
        float ta[6];
        #pragma unroll
        for (int m = 0; m < 6; ++m) ta[m] = row[m];
        #pragma unroll
        for (int j = 0; j < KDIM; ++j) {
            const int kk = i * KDIM + j;
            f2 nkv = *reinterpret_cast<const f2*>(&nnk[kk * NPIX + n]);
            #pragma unroll
            for (int q = 0; q < PXT; ++q) {
                float d = (nkv[q] > 1e-6f) ? ta[q + j] * fac[q] : 0.0f;
                float v = nkv[q] + 0.01f * d;
                v = fmaxf(v, 0.0f);
                if (kk == KK / 2) v = 0.0f;
                colsum[q] += v;
            }
        }
    }

    f2 scale;
    #pragma unroll
    for (int q = 0; q < PXT; ++q) {
        float ks = (ei[q] < 0.0f) ? kI[q] : kE[q];
        scale[q] = ks / (colsum[q] + 1e-6f);
    }

    // P3: recompute (bit-identical) and store scaled weights
    #pragma unroll
    for (int i = 0; i < KDIM; ++i) {
        const float* row = &at[ly + i][lx * PXT + 2];
        float ta[6];
        #pragma unroll
        for (int m = 0; m < 6; ++m) ta[m] = row[m];
        #pragma unroll
        for (int j = 0; j < KDIM; ++j) {
            const int kk = i * KDIM + j;
            f2 nkv = *reinterpret_cast<const f2*>(&nnk[kk * NPIX + n]);
            f2 vout;
            #pragma unroll
            for (int q = 0; q < PXT; ++q) {
                float d = (nkv[q] > 1e-6f) ? ta[q + j] * fac[q] : 0.0f;
                float v = nkv[q] + 0.01f * d;
                v = fmaxf(v, 0.0f);
                if (kk == KK / 2) v = 0.0f;
                vout[q] = v * scale[q];
            }
            __builtin_nontemporal_store(vout,
                reinterpret_cast<f2*>(&out[(7 + kk) * NPIX + n]));
        }
    }
}

extern "C" void kernel_launch(void* const* d_in, const int* in_sizes, int n_in,
                              void* d_out, int out_size, void* d_ws, size_t ws_size,
                              hipStream_t stream) {
    const float* x    = (const float*)d_in[0];
    const float* EI   = (const float*)d_in[2];
    const float* nnk  = (const float*)d_in[3];
    const float* trm  = (const float*)d_in[4];
    const float* ksI  = (const float*)d_in[6];
    const float* ksE  = (const float*)d_in[7];
    float* out = (float*)d_out;

    dim3 block(TX, TY);
    dim3 grid(WDIM / TILEW, HDIM / TY);   // 16 x 128 = 2048 blocks
    fused_step<<<grid, block, 0, stream>>>(x, EI, nnk, trm, ksI, ksE, out);
}

// Round 6
// 46.869 us; speedup vs baseline: 4.5597x; 4.1744x over previous
//
#include <hip/hip_runtime.h>

#define HDIM 1024
#define WDIM 1024
#define NPIX (HDIM*WDIM)
#define KDIM 5
#define KK 25
#define TX 32
#define TY 8
#define NTHR (TX*TY)           // 256
#define PXT 2                  // pixels per thread
#define TILEW (TX*PXT)         // 64
#define TROWS (TY + 4)         // 12
#define NF4 18                 // staged f4 per row: cols [bx-4, bx+68)
#define TCOLS 76               // 72 used + 4 pad floats

typedef float f4 __attribute__((ext_vector_type(4)));
typedef float f2 __attribute__((ext_vector_type(2)));

__global__ __launch_bounds__(NTHR) void fused_step(
    const float* __restrict__ x,     // 6*N  [spike, V, R, A, T, E]
    const float* __restrict__ EI,    // N
    const float* __restrict__ nnk,   // 25*N
    const float* __restrict__ trm,   // N
    const float* __restrict__ ksI,   // N
    const float* __restrict__ ksE,   // N
    float* __restrict__ out)         // 32*N  [z(7N), new_k(25N)]
{
#pragma clang fp contract(off)
    __shared__ __align__(16) float s0t[TROWS][TCOLS];
    __shared__ __align__(16) float at [TROWS][TCOLS];

    const int bx  = blockIdx.x * TILEW;
    const int by  = blockIdx.y * TY;
    const int tid = threadIdx.y * TX + threadIdx.x;
    const int lx  = threadIdx.x;
    const int ly  = threadIdx.y;
    const int n   = (by + ly) * WDIM + bx + lx * PXT;

    // Issue the 25 nn_k loads first — they overlap the staging + barrier.
    f2 nk[KK];
    #pragma unroll
    for (int kk = 0; kk < KK; ++kk)
        nk[kk] = *reinterpret_cast<const f2*>(&nnk[kk * NPIX + n]);

    // vectorized halo staging: aligned f4, circular wrap (bases 4-aligned)
    for (int idx = tid; idx < TROWS * NF4; idx += NTHR) {
        int r  = idx / NF4;
        int t  = idx - r * NF4;
        int gy = (by + r - 2) & (HDIM - 1);
        int gx = (bx - 4 + t * 4) & (WDIM - 1);
        int g  = gy * WDIM + gx;
        f4 x0 = *reinterpret_cast<const f4*>(&x[g]);
        f4 ev = *reinterpret_cast<const f4*>(&EI[g]);
        f4 a3 = *reinterpret_cast<const f4*>(&x[3 * NPIX + g]);
        f4 s0;
        #pragma unroll
        for (int q = 0; q < 4; ++q) s0[q] = x0[q] * ev[q];
        *reinterpret_cast<f4*>(&s0t[r][t * 4]) = s0;
        *reinterpret_cast<f4*>(&at [r][t * 4]) = a3;
    }
    __syncthreads();

    // LDS col c maps to gx = bx-4+c; tap for pixel q, offset j: c = lx*2+2+q+j

    // P1: conv accumulate (sequential kk order, no fma)
    f2 I = {0.0f, 0.0f};
    #pragma unroll
    for (int i = 0; i < KDIM; ++i) {
        const float* row = &s0t[ly + i][lx * PXT + 2];
        float ta[6];
        #pragma unroll
        for (int m = 0; m < 6; ++m) ta[m] = row[m];
        #pragma unroll
        for (int j = 0; j < KDIM; ++j) {
            const int kk = i * KDIM + j;
            #pragma unroll
            for (int q = 0; q < PXT; ++q) {
                float p = ta[q + j] * nk[kk][q];
                I[q] = I[q] + p;
            }
        }
    }

    // pointwise neuron update
    f2 V  = *reinterpret_cast<const f2*>(&x[1 * NPIX + n]);
    f2 R  = *reinterpret_cast<const f2*>(&x[2 * NPIX + n]);
    f2 A  = *reinterpret_cast<const f2*>(&x[3 * NPIX + n]);
    f2 T  = *reinterpret_cast<const f2*>(&x[4 * NPIX + n]);
    f2 E  = *reinterpret_cast<const f2*>(&x[5 * NPIX + n]);
    f2 ei = *reinterpret_cast<const f2*>(&EI[n]);
    f2 tr = *reinterpret_cast<const f2*>(&trm[n]);
    f2 kI = *reinterpret_cast<const f2*>(&ksI[n]);
    f2 kE = *reinterpret_cast<const f2*>(&ksE[n]);

    f2 S, Vo, Rn, An, Tn, En, fac;
    #pragma unroll
    for (int q = 0; q < PXT; ++q) {
        float v = (V[q] - 0.2f * V[q]) + 4.0f * I[q];
        float s = (v > T[q] && R[q] > 5.0f && E[q] > 0.1f) ? 1.0f : 0.0f;
        En[q] = (E[q] + 0.0058f * (1.0f - E[q])) - s * 0.1f;
        Rn[q] = (R[q] + 1.0f) * (1.0f - s);
        float an = (A[q] - A[q] / 100.0f) + s;
        An[q] = an;
        Tn[q] = (T[q] - T[q] / 1000.0f) + 0.05f * (an - tr[q]);
        Vo[q] = v * (1.0f - s);
        S[q]  = s;
        float ei_neg = (ei[q] < 0.0f) ? 1.0f : 0.0f;
        fac[q] = an - tr[q] * ei_neg;
    }

    // store z now to free state registers
    __builtin_nontemporal_store(S,  reinterpret_cast<f2*>(&out[0 * NPIX + n]));
    __builtin_nontemporal_store(Vo, reinterpret_cast<f2*>(&out[1 * NPIX + n]));
    __builtin_nontemporal_store(Rn, reinterpret_cast<f2*>(&out[2 * NPIX + n]));
    __builtin_nontemporal_store(An, reinterpret_cast<f2*>(&out[3 * NPIX + n]));
    __builtin_nontemporal_store(Tn, reinterpret_cast<f2*>(&out[4 * NPIX + n]));
    __builtin_nontemporal_store(En, reinterpret_cast<f2*>(&out[5 * NPIX + n]));
    __builtin_nontemporal_store(ei, reinterpret_cast<f2*>(&out[6 * NPIX + n]));

    // Hebbian update + column sum (nk in registers)
    f2 colsum = {0.0f, 0.0f};
    #pragma unroll
    for (int i = 0; i < KDIM; ++i) {
        const float* row = &at[ly + i][lx * PXT + 2];
        float ta[6];
        #pragma unroll
        for (int m = 0; m < 6; ++m) ta[m] = row[m];
        #pragma unroll
        for (int j = 0; j < KDIM; ++j) {
            const int kk = i * KDIM + j;
            #pragma unroll
            for (int q = 0; q < PXT; ++q) {
                float d = (nk[kk][q] > 1e-6f) ? ta[q + j] * fac[q] : 0.0f;
                float v = nk[kk][q] + 0.01f * d;
                v = fmaxf(v, 0.0f);
                if (kk == KK / 2) v = 0.0f;
                nk[kk][q] = v;
                colsum[q] += v;
            }
        }
    }

    f2 scale;
    #pragma unroll
    for (int q = 0; q < PXT; ++q) {
        float ks = (ei[q] < 0.0f) ? kI[q] : kE[q];
        scale[q] = ks / (colsum[q] + 1e-6f);
    }

    #pragma unroll
    for (int kk = 0; kk < KK; ++kk) {
        f2 v;
        #pragma unroll
        for (int q = 0; q < PXT; ++q) v[q] = nk[kk][q] * scale[q];
        __builtin_nontemporal_store(v,
            reinterpret_cast<f2*>(&out[(7 + kk) * NPIX + n]));
    }
}

extern "C" void kernel_launch(void* const* d_in, const int* in_sizes, int n_in,
                              void* d_out, int out_size, void* d_ws, size_t ws_size,
                              hipStream_t stream) {
    const float* x    = (const float*)d_in[0];
    const float* EI   = (const float*)d_in[2];
    const float* nnk  = (const float*)d_in[3];
    const float* trm  = (const float*)d_in[4];
    const float* ksI  = (const float*)d_in[6];
    const float* ksE  = (const float*)d_in[7];
    float* out = (float*)d_out;

    dim3 block(TX, TY);
    dim3 grid(WDIM / TILEW, HDIM / TY);   // 16 x 128 = 2048 blocks
    fused_step<<<grid, block, 0, stream>>>(x, EI, nnk, trm, ksI, ksE, out);
}

// Round 7
// 44.794 us; speedup vs baseline: 4.7709x; 1.0463x over previous
//
#include <hip/hip_runtime.h>

#define HDIM 1024
#define WDIM 1024
#define NPIX (HDIM*WDIM)
#define KDIM 5
#define KK 25
#define TX 64
#define TY 4
#define NTHR (TX*TY)           // 256
#define PXT 2                  // pixels per thread
#define TILEW (TX*PXT)         // 128
#define GX (WDIM/TILEW)        // 8 blocks per pixel-row band
#define GY (HDIM/TY)           // 256
#define NWG (GX*GY)            // 2048

typedef float f2 __attribute__((ext_vector_type(2)));

__global__ __launch_bounds__(NTHR) void fused_step(
    const float* __restrict__ x,     // 6*N  [spike, V, R, A, T, E]
    const float* __restrict__ EI,    // N
    const float* __restrict__ nnk,   // 25*N
    const float* __restrict__ trm,   // N
    const float* __restrict__ ksI,   // N
    const float* __restrict__ ksE,   // N
    float* __restrict__ out)         // 32*N  [z(7N), new_k(25N)]
{
#pragma clang fp contract(off)
    // Bijective XCD band swizzle: each of 8 XCDs gets 256 consecutive wgids
    // = a contiguous 128-pixel-row band (halo rows stay in that XCD's L2).
    const int orig = blockIdx.x;                 // 0..2047
    const int wgid = (orig & 7) * (NWG / 8) + (orig >> 3);
    const int bx   = (wgid % GX) * TILEW;
    const int by   = (wgid / GX) * TY;

    const int lx = threadIdx.x;                  // 0..63 (one wave = one row)
    const int ly = threadIdx.y;                  // 0..3
    const int y  = by + ly;
    const int c  = bx + lx * PXT;                // even
    const int n  = y * WDIM + c;

    const int cm2 = (c - 2) & (WDIM - 1);        // aligned f2 pair col
    const int cp2 = (c + 2) & (WDIM - 1);

    // nn_k loads issued first: 25 independent dwordx2, overlap everything.
    f2 nk[KK];
    #pragma unroll
    for (int kk = 0; kk < KK; ++kk)
        nk[kk] = *reinterpret_cast<const f2*>(&nnk[kk * NPIX + n]);

    // P1: conv accumulate straight from global (L1/L2-served neighborhood).
    f2 I = {0.0f, 0.0f};
    #pragma unroll
    for (int i = 0; i < KDIM; ++i) {
        const int rb = ((y + i - 2) & (HDIM - 1)) * WDIM;
        f2 xa = *reinterpret_cast<const f2*>(&x[rb + cm2]);
        f2 xb = *reinterpret_cast<const f2*>(&x[rb + c]);
        f2 xc = *reinterpret_cast<const f2*>(&x[rb + cp2]);
        f2 ea = *reinterpret_cast<const f2*>(&EI[rb + cm2]);
        f2 eb = *reinterpret_cast<const f2*>(&EI[rb + c]);
        f2 ec = *reinterpret_cast<const f2*>(&EI[rb + cp2]);
        float s0v[6] = {xa[0]*ea[0], xa[1]*ea[1], xb[0]*eb[0],
                        xb[1]*eb[1], xc[0]*ec[0], xc[1]*ec[1]};
        #pragma unroll
        for (int j = 0; j < KDIM; ++j) {
            const int kk = i * KDIM + j;
            #pragma unroll
            for (int q = 0; q < PXT; ++q) {
                float p = s0v[q + j] * nk[kk][q];
                I[q] = I[q] + p;
            }
        }
    }

    // pointwise neuron update
    f2 V  = *reinterpret_cast<const f2*>(&x[1 * NPIX + n]);
    f2 R  = *reinterpret_cast<const f2*>(&x[2 * NPIX + n]);
    f2 A  = *reinterpret_cast<const f2*>(&x[3 * NPIX + n]);
    f2 T  = *reinterpret_cast<const f2*>(&x[4 * NPIX + n]);
    f2 E  = *reinterpret_cast<const f2*>(&x[5 * NPIX + n]);
    f2 ei = *reinterpret_cast<const f2*>(&EI[n]);
    f2 tr = *reinterpret_cast<const f2*>(&trm[n]);
    f2 kI = *reinterpret_cast<const f2*>(&ksI[n]);
    f2 kE = *reinterpret_cast<const f2*>(&ksE[n]);

    f2 S, Vo, Rn, An, Tn, En, fac;
    #pragma unroll
    for (int q = 0; q < PXT; ++q) {
        float v = (V[q] - 0.2f * V[q]) + 4.0f * I[q];
        float s = (v > T[q] && R[q] > 5.0f && E[q] > 0.1f) ? 1.0f : 0.0f;
        En[q] = (E[q] + 0.0058f * (1.0f - E[q])) - s * 0.1f;
        Rn[q] = (R[q] + 1.0f) * (1.0f - s);
        float an = (A[q] - A[q] / 100.0f) + s;
        An[q] = an;
        Tn[q] = (T[q] - T[q] / 1000.0f) + 0.05f * (an - tr[q]);
        Vo[q] = v * (1.0f - s);
        S[q]  = s;
        float ei_neg = (ei[q] < 0.0f) ? 1.0f : 0.0f;
        fac[q] = an - tr[q] * ei_neg;
    }

    __builtin_nontemporal_store(S,  reinterpret_cast<f2*>(&out[0 * NPIX + n]));
    __builtin_nontemporal_store(Vo, reinterpret_cast<f2*>(&out[1 * NPIX + n]));
    __builtin_nontemporal_store(Rn, reinterpret_cast<f2*>(&out[2 * NPIX + n]));
    __builtin_nontemporal_store(An, reinterpret_cast<f2*>(&out[3 * NPIX + n]));
    __builtin_nontemporal_store(Tn, reinterpret_cast<f2*>(&out[4 * NPIX + n]));
    __builtin_nontemporal_store(En, reinterpret_cast<f2*>(&out[5 * NPIX + n]));
    __builtin_nontemporal_store(ei, reinterpret_cast<f2*>(&out[6 * NPIX + n]));

    // P2: Hebbian update + column sum (A neighborhood direct from global,
    // rows are L2-hot; nk stays in registers)
    f2 colsum = {0.0f, 0.0f};
    #pragma unroll
    for (int i = 0; i < KDIM; ++i) {
        const int rb = 3 * NPIX + ((y + i - 2) & (HDIM - 1)) * WDIM;
        f2 aa = *reinterpret_cast<const f2*>(&x[rb + cm2]);
        f2 ab = *reinterpret_cast<const f2*>(&x[rb + c]);
        f2 ac = *reinterpret_cast<const f2*>(&x[rb + cp2]);
        float pre[6] = {aa[0], aa[1], ab[0], ab[1], ac[0], ac[1]};
        #pragma unroll
        for (int j = 0; j < KDIM; ++j) {
            const int kk = i * KDIM + j;
            #pragma unroll
            for (int q = 0; q < PXT; ++q) {
                float d = (nk[kk][q] > 1e-6f) ? pre[q + j] * fac[q] : 0.0f;
                float v = nk[kk][q] + 0.01f * d;
                v = fmaxf(v, 0.0f);
                if (kk == KK / 2) v = 0.0f;
                nk[kk][q] = v;
                colsum[q] += v;
            }
        }
    }

    f2 scale;
    #pragma unroll
    for (int q = 0; q < PXT; ++q) {
        float ks = (ei[q] < 0.0f) ? kI[q] : kE[q];
        scale[q] = ks / (colsum[q] + 1e-6f);
    }

    #pragma unroll
    for (int kk = 0; kk < KK; ++kk) {
        f2 v;
        #pragma unroll
        for (int q = 0; q < PXT; ++q) v[q] = nk[kk][q] * scale[q];
        __builtin_nontemporal_store(v,
            reinterpret_cast<f2*>(&out[(7 + kk) * NPIX + n]));
    }
}

extern "C" void kernel_launch(void* const* d_in, const int* in_sizes, int n_in,
                              void* d_out, int out_size, void* d_ws, size_t ws_size,
                              hipStream_t stream) {
    const float* x    = (const float*)d_in[0];
    const float* EI   = (const float*)d_in[2];
    const float* nnk  = (const float*)d_in[3];
    const float* trm  = (const float*)d_in[4];
    const float* ksI  = (const float*)d_in[6];
    const float* ksE  = (const float*)d_in[7];
    float* out = (float*)d_out;

    dim3 block(TX, TY);
    fused_step<<<dim3(NWG), block, 0, stream>>>(x, EI, nnk, trm, ksI, ksE, out);
}

// Round 8
// 44.223 us; speedup vs baseline: 4.8325x; 1.0129x over previous
//
#include <hip/hip_runtime.h>

#define HDIM 1024
#define WDIM 1024
#define NPIX (HDIM*WDIM)
#define KDIM 5
#define KK 25
#define TX 64
#define TY 4
#define NTHR (TX*TY)           // 256
#define PXT 2                  // pixels per thread
#define TILEW (TX*PXT)         // 128
#define GX (WDIM/TILEW)        // 8
#define GY (HDIM/TY)           // 256
#define NWG (GX*GY)            // 2048

typedef float f2 __attribute__((ext_vector_type(2)));

__global__ __launch_bounds__(NTHR) void fused_step(
    const float* __restrict__ x,     // 6*N  [spike, V, R, A, T, E]
    const float* __restrict__ EI,    // N
    const float* __restrict__ nnk,   // 25*N
    const float* __restrict__ trm,   // N
    const float* __restrict__ ksI,   // N
    const float* __restrict__ ksE,   // N
    float* __restrict__ out)         // 32*N  [z(7N), new_k(25N)]
{
#pragma clang fp contract(off)
    // Bijective XCD band swizzle (2048 % 8 == 0): each XCD owns a contiguous
    // 128-pixel-row band so halo rows hit its own L2.
    const int orig = blockIdx.x;
    const int wgid = (orig & 7) * (NWG / 8) + (orig >> 3);
    const int bx   = (wgid % GX) * TILEW;
    const int by   = (wgid / GX) * TY;

    const int lx = threadIdx.x;                  // 0..63, one wave = one row
    const int ly = threadIdx.y;
    const int y  = by + ly;
    const int c  = bx + lx * PXT;                // even
    const int n  = y * WDIM + c;

    const int cm2 = (c - 2) & (WDIM - 1);
    const int cp2 = (c + 2) & (WDIM - 1);

    // ---- issue ALL independent loads up front (max per-wave MLP) ----
    f2 nk[KK];
    #pragma unroll
    for (int kk = 0; kk < KK; ++kk)
        nk[kk] = *reinterpret_cast<const f2*>(&nnk[kk * NPIX + n]);

    // A (ch3) 5-row neighborhood — feeds the Hebbian pass, held in regs
    f2 pa[KDIM][3];
    #pragma unroll
    for (int i = 0; i < KDIM; ++i) {
        const int rb = 3 * NPIX + ((y + i - 2) & (HDIM - 1)) * WDIM;
        pa[i][0] = *reinterpret_cast<const f2*>(&x[rb + cm2]);
        pa[i][1] = *reinterpret_cast<const f2*>(&x[rb + c]);
        pa[i][2] = *reinterpret_cast<const f2*>(&x[rb + cp2]);
    }

    f2 V  = *reinterpret_cast<const f2*>(&x[1 * NPIX + n]);
    f2 R  = *reinterpret_cast<const f2*>(&x[2 * NPIX + n]);
    f2 T  = *reinterpret_cast<const f2*>(&x[4 * NPIX + n]);
    f2 E  = *reinterpret_cast<const f2*>(&x[5 * NPIX + n]);
    f2 ei = *reinterpret_cast<const f2*>(&EI[n]);
    f2 tr = *reinterpret_cast<const f2*>(&trm[n]);
    f2 kI = *reinterpret_cast<const f2*>(&ksI[n]);
    f2 kE = *reinterpret_cast<const f2*>(&ksE[n]);
    f2 A  = pa[2][1];                            // dedup: center of A-nbhd

    // ---- P1: conv accumulate (per-row x/EI loads; sequential kk, no fma) ----
    f2 I = {0.0f, 0.0f};
    #pragma unroll
    for (int i = 0; i < KDIM; ++i) {
        const int rb = ((y + i - 2) & (HDIM - 1)) * WDIM;
        f2 xa = *reinterpret_cast<const f2*>(&x[rb + cm2]);
        f2 xb = *reinterpret_cast<const f2*>(&x[rb + c]);
        f2 xc = *reinterpret_cast<const f2*>(&x[rb + cp2]);
        f2 ea = *reinterpret_cast<const f2*>(&EI[rb + cm2]);
        f2 eb = *reinterpret_cast<const f2*>(&EI[rb + c]);
        f2 ec = *reinterpret_cast<const f2*>(&EI[rb + cp2]);
        float s0v[6] = {xa[0]*ea[0], xa[1]*ea[1], xb[0]*eb[0],
                        xb[1]*eb[1], xc[0]*ec[0], xc[1]*ec[1]};
        #pragma unroll
        for (int j = 0; j < KDIM; ++j) {
            const int kk = i * KDIM + j;
            #pragma unroll
            for (int q = 0; q < PXT; ++q) {
                float p = s0v[q + j] * nk[kk][q];
                I[q] = I[q] + p;
            }
        }
    }

    // ---- pointwise neuron update ----
    f2 S, Vo, Rn, An, Tn, En, fac;
    #pragma unroll
    for (int q = 0; q < PXT; ++q) {
        float v = (V[q] - 0.2f * V[q]) + 4.0f * I[q];
        float s = (v > T[q] && R[q] > 5.0f && E[q] > 0.1f) ? 1.0f : 0.0f;
        En[q] = (E[q] + 0.0058f * (1.0f - E[q])) - s * 0.1f;
        Rn[q] = (R[q] + 1.0f) * (1.0f - s);
        float an = (A[q] - A[q] / 100.0f) + s;
        An[q] = an;
        Tn[q] = (T[q] - T[q] / 1000.0f) + 0.05f * (an - tr[q]);
        Vo[q] = v * (1.0f - s);
        S[q]  = s;
        float ei_neg = (ei[q] < 0.0f) ? 1.0f : 0.0f;
        fac[q] = an - tr[q] * ei_neg;
    }

    __builtin_nontemporal_store(S,  reinterpret_cast<f2*>(&out[0 * NPIX + n]));
    __builtin_nontemporal_store(Vo, reinterpret_cast<f2*>(&out[1 * NPIX + n]));
    __builtin_nontemporal_store(Rn, reinterpret_cast<f2*>(&out[2 * NPIX + n]));
    __builtin_nontemporal_store(An, reinterpret_cast<f2*>(&out[3 * NPIX + n]));
    __builtin_nontemporal_store(Tn, reinterpret_cast<f2*>(&out[4 * NPIX + n]));
    __builtin_nontemporal_store(En, reinterpret_cast<f2*>(&out[5 * NPIX + n]));
    __builtin_nontemporal_store(ei, reinterpret_cast<f2*>(&out[6 * NPIX + n]));

    // ---- P2: Hebbian update + column sum, entirely from registers ----
    f2 colsum = {0.0f, 0.0f};
    #pragma unroll
    for (int i = 0; i < KDIM; ++i) {
        float pre[6] = {pa[i][0][0], pa[i][0][1], pa[i][1][0],
                        pa[i][1][1], pa[i][2][0], pa[i][2][1]};
        #pragma unroll
        for (int j = 0; j < KDIM; ++j) {
            const int kk = i * KDIM + j;
            #pragma unroll
            for (int q = 0; q < PXT; ++q) {
                float d = (nk[kk][q] > 1e-6f) ? pre[q + j] * fac[q] : 0.0f;
                float v = nk[kk][q] + 0.01f * d;
                v = fmaxf(v, 0.0f);
                if (kk == KK / 2) v = 0.0f;
                nk[kk][q] = v;
                colsum[q] += v;
            }
        }
    }

    f2 scale;
    #pragma unroll
    for (int q = 0; q < PXT; ++q) {
        float ks = (ei[q] < 0.0f) ? kI[q] : kE[q];
        scale[q] = ks / (colsum[q] + 1e-6f);
    }

    #pragma unroll
    for (int kk = 0; kk < KK; ++kk) {
        f2 v;
        #pragma unroll
        for (int q = 0; q < PXT; ++q) v[q] = nk[kk][q] * scale[q];
        __builtin_nontemporal_store(v,
            reinterpret_cast<f2*>(&out[(7 + kk) * NPIX + n]));
    }
}

extern "C" void kernel_launch(void* const* d_in, const int* in_sizes, int n_in,
                              void* d_out, int out_size, void* d_ws, size_t ws_size,
                              hipStream_t stream) {
    const float* x    = (const float*)d_in[0];
    const float* EI   = (const float*)d_in[2];
    const float* nnk  = (const float*)d_in[3];
    const float* trm  = (const float*)d_in[4];
    const float* ksI  = (const float*)d_in[6];
    const float* ksE  = (const float*)d_in[7];
    float* out = (float*)d_out;

    dim3 block(TX, TY);
    fused_step<<<dim3(NWG), block, 0, stream>>>(x, EI, nnk, trm, ksI, ksE, out);
}